// Round 12
// baseline (157.031 us; speedup 1.0000x reference)
//
#include <hip/hip_runtime.h>
#include <hip/hip_bf16.h>

// ---------------------------------------------------------------------------
// Fused: LN -> qkv GEMM (+RoPE/bilinear/v-transpose epilogues) -> flash attn
//        (j-split x2, fence-free merge kernel) -> out GEMM.
// B=1, N=2048, DIM=1024, HEADS=16, DHEAD=64.
// R12 = R11 with the merge_kernel writeout bug fixed: the final aout store
//       covered only e in [0,32) (c = t>>6 spans 4 of 8 row chunks) -> half
//       of every head's output stayed poison => absmax 3.6e-2.  Now each
//       thread writes chunks c and c+4 (full 64-e coverage).
// 5 launches: prep, gemm_qkv, attn, merge, gemm64.
// ---------------------------------------------------------------------------

typedef unsigned short u16;
typedef __attribute__((ext_vector_type(4))) float f32x4;
typedef __attribute__((ext_vector_type(8))) __bf16 bf16x8;

struct alignas(8) US4 { u16 x, y, z, w; };

__device__ __forceinline__ u16 f2bf(float f) {
  union { float f; unsigned u; } v; v.f = f;
  unsigned r = v.u + 0x7FFFu + ((v.u >> 16) & 1u);   // RNE
  return (u16)(r >> 16);
}
// packed f32 pair -> bf16x2 (v_cvt_pk_bf16_f32, RNE -- bit-identical to f2bf)
__device__ __forceinline__ unsigned pk2bf(float a, float b) {
  float2 f; f.x = a; f.y = b;
  __hip_bfloat162 h = __float22bfloat162_rn(f);
  union { __hip_bfloat162 h; unsigned u; } v; v.h = h;
  return v.u;
}

typedef void GVOID __attribute__((address_space(1)));
typedef void LVOID __attribute__((address_space(3)));

#if defined(__has_builtin)
#if __has_builtin(__builtin_amdgcn_global_load_lds)
#define HAS_GLD_LDS 1
#endif
#endif

__device__ __forceinline__ void gld16(const void* g, void* l) {
#ifdef HAS_GLD_LDS
  __builtin_amdgcn_global_load_lds((GVOID*)(void*)g, (LVOID*)l, 16, 0, 0);
#else
  struct alignas(16) U4 { unsigned a, b, c, d; };
  *(U4*)l = *(const U4*)g;
#endif
}

__device__ __forceinline__ f32x4 MFMA(bf16x8 a, bf16x8 b, f32x4 c) {
  return __builtin_amdgcn_mfma_f32_16x16x32_bf16(a, b, c, 0, 0, 0);
}

// LDS swizzle for 64B-row tiles (32 u16/row, 4 x 16B chunks)
__device__ __forceinline__ int swz(int r, int q) {   // u16 index
  return r * 32 + ((q ^ ((r >> 1) & 3)) << 3);
}
__device__ __forceinline__ int swz_src_colb(int o) { // byte offset in 64B row
  const int r = o >> 6;
  return ((((o >> 4) & 3) ^ ((r >> 1) & 3)) << 4);
}
// merge-phase f32 [64][64] arrays: 16B chunk c of row ee at chunk c^(ee&15)
__device__ __forceinline__ int mswz4(int ee, int c) {  // f32 idx, 16B chunk
  return ee * 64 + ((c ^ (ee & 15)) << 2);
}

// ---------------------------------------------------------------------------
// prep: weight transposes (+bf16 cast) and LayerNorm in one launch.
// ---------------------------------------------------------------------------
__global__ __launch_bounds__(256) void prep_kernel(
    const float* __restrict__ x, const float* __restrict__ gamma,
    const float* __restrict__ Wq, const float* __restrict__ Wkv,
    const float* __restrict__ Wo, const float* __restrict__ Wb,
    u16* __restrict__ xn, u16* __restrict__ wqkvT, u16* __restrict__ woT,
    u16* __restrict__ wbT) {
  __shared__ __align__(16) float smem[32 * 33];
  const int bid = blockIdx.x, t = threadIdx.x;
  if (bid < 4160) {
    const float* src; u16* dst; int C, R, bx, by;
    if (bid < 1024)      { src = Wq;  dst = wqkvT;              R = 1024; C = 1024; bx = bid & 31; by = bid >> 5; }
    else if (bid < 3072) { int i = bid - 1024; src = Wkv; dst = wqkvT + 1024 * 1024; R = 1024; C = 2048; bx = i & 63; by = i >> 6; }
    else if (bid < 4096) { int i = bid - 3072; src = Wo;  dst = woT; R = 1024; C = 1024; bx = i & 31; by = i >> 5; }
    else { int i = bid - 4096; int h = i >> 2; src = Wb + (size_t)h * 4096; dst = wbT + (size_t)h * 4096; R = 64; C = 64; bx = i & 1; by = (i >> 1) & 1; }
    float (*tile)[33] = (float(*)[33])smem;
    const int c0 = bx * 32, r0 = by * 32;
    const int tx = t & 31, ty = t >> 5;  // 32 x 8
#pragma unroll
    for (int i = 0; i < 4; i++)
      tile[ty + i * 8][tx] = src[(size_t)(r0 + ty + i * 8) * C + c0 + tx];
    __syncthreads();
#pragma unroll
    for (int i = 0; i < 4; i++)
      dst[(size_t)(c0 + ty + i * 8) * R + r0 + tx] = f2bf(tile[tx][ty + i * 8]);
  } else {
    const int n = bid - 4160;
    const int w = t >> 6, lane = t & 63;
    const float4 v = *(const float4*)&x[(size_t)n * 1024 + t * 4];
    float s = v.x + v.y + v.z + v.w;
    float q = v.x * v.x + v.y * v.y + v.z * v.z + v.w * v.w;
#pragma unroll
    for (int off = 32; off; off >>= 1) {
      s += __shfl_down(s, off);
      q += __shfl_down(q, off);
    }
    if (lane == 0) { smem[w] = s; smem[4 + w] = q; }
    __syncthreads();
    s = smem[0] + smem[1] + smem[2] + smem[3];
    q = smem[4] + smem[5] + smem[6] + smem[7];
    const float mean = s * (1.0f / 1024.0f);
    const float var = q * (1.0f / 1024.0f) - mean * mean;
    const float inv = rsqrtf(var + 1e-5f);
    const float4 g = *(const float4*)&gamma[t * 4];
    US4 o;
    o.x = f2bf((v.x - mean) * inv * g.x);
    o.y = f2bf((v.y - mean) * inv * g.y);
    o.z = f2bf((v.z - mean) * inv * g.z);
    o.w = f2bf((v.w - mean) * inv * g.w);
    *(US4*)&xn[(size_t)n * 1024 + t * 4] = o;
  }
}

// ---------------------------------------------------------------------------
// qkv GEMM, 128x128 tile, BK=64, grid (24,16).  Epilogues by region:
//   q: rope*0.125 -> qh | k: rope -> LDS -> @wbT -> kth | v: cast -> vt.
// LDS: As 16K + Bs 16K + krs 32K = 64KB -> 2 blocks/CU.
// ---------------------------------------------------------------------------
__global__ __launch_bounds__(256, 2) void gemm_qkv(
    const u16* __restrict__ A, const u16* __restrict__ B,
    const u16* __restrict__ wbT, u16* __restrict__ qh,
    u16* __restrict__ kth, u16* __restrict__ vt) {
  __shared__ u16 As[2 * 128 * 32];   // 16KB [ksub][row128][k32] swz
  __shared__ u16 Bs[2 * 128 * 32];   // 16KB
  __shared__ u16 krs[2 * 8192];      // 32KB: [head2][dsub2][row128][d32] swz
  const int K = 1024;
  const int t = threadIdx.x;
  const int w = t >> 6, lane = t & 63, quad = lane >> 4, cc = lane & 15;
  const int bm = blockIdx.y << 7, bn = blockIdx.x << 7;
  const int wm = (w >> 1) << 6, wn = (w & 1) << 6;
  const f32x4 fzero = {0.f, 0.f, 0.f, 0.f};
  f32x4 acc[4][4];
#pragma unroll
  for (int i = 0; i < 4; i++)
#pragma unroll
    for (int j = 0; j < 4; j++) acc[i][j] = fzero;

  const char* gA = (const char*)A;
  const char* gB = (const char*)B;
  for (int k0 = 0; k0 < K; k0 += 64) {
    __syncthreads();
#pragma unroll
    for (int i = 0; i < 4; i++) {
      const int o = (i * 256 + t) * 16;
      const int sub = o >> 13, row = (o >> 6) & 127, colb = swz_src_colb(o);
      gld16(gA + (((size_t)(bm + row) * K + k0 + sub * 32) << 1) + colb, (char*)As + o);
      gld16(gB + (((size_t)(bn + row) * K + k0 + sub * 32) << 1) + colb, (char*)Bs + o);
    }
    __syncthreads();
#pragma unroll
    for (int ks = 0; ks < 2; ks++) {
      bf16x8 af[4], bfr[4];
#pragma unroll
      for (int mi = 0; mi < 4; mi++)
        af[mi] = *(const bf16x8*)&As[ks * 4096 + swz(wm + mi * 16 + cc, quad)];
#pragma unroll
      for (int ni = 0; ni < 4; ni++)
        bfr[ni] = *(const bf16x8*)&Bs[ks * 4096 + swz(wn + ni * 16 + cc, quad)];
#pragma unroll
      for (int mi = 0; mi < 4; mi++)
#pragma unroll
        for (int ni = 0; ni < 4; ni++)
          acc[mi][ni] = MFMA(af[mi], bfr[ni], acc[mi][ni]);
    }
  }

  const int region = blockIdx.x >> 3;  // 0=q, 1=k, 2=v (uniform per block)
  if (region == 0) {
    // ---- q: rope * 0.125 -> qh ----
#pragma unroll
    for (int ni = 0; ni < 4; ni++) {
      const int col = bn + wn + ni * 16 + cc;
      const int h = (col >> 6) & 15, d = col & 63;
      const float theta = __expf(-(float)(col & 31) * 0.2878231366242557f);
      const float sgn = (col & 1) ? 1.0f : -1.0f;
#pragma unroll
      for (int mi = 0; mi < 4; mi++) {
        const int row0 = bm + wm + mi * 16 + quad * 4;
#pragma unroll
        for (int r = 0; r < 4; r++) {
          const float val = acc[mi][ni][r];
          const float pr = __shfl_xor(val, 1);
          float sv, cv;
          __sincosf(theta * (float)(row0 + r), &sv, &cv);
          qh[((size_t)h * 2048 + row0 + r) * 64 + d] =
              f2bf((val * cv + sgn * pr * sv) * 0.125f);
        }
      }
    }
  } else if (region == 2) {
    // ---- v: direct transpose write vt[h][d][n] ----
#pragma unroll
    for (int ni = 0; ni < 4; ni++) {
      const int col = bn + wn + ni * 16 + cc;
      const int h = (col >> 6) & 15, d = col & 63;
      u16* base = vt + ((size_t)h * 64 + d) * 2048;
#pragma unroll
      for (int mi = 0; mi < 4; mi++) {
        const int row0 = bm + wm + mi * 16 + quad * 4;
        uint2 pk;
        pk.x = pk2bf(acc[mi][ni][0], acc[mi][ni][1]);
        pk.y = pk2bf(acc[mi][ni][2], acc[mi][ni][3]);
        *(uint2*)&base[row0] = pk;
      }
    }
  } else {
    // ---- k: rope -> krs (A-layout, swz) ----
    const int h2 = w & 1;
    u16* krh = krs + h2 * 8192;
#pragma unroll
    for (int ni = 0; ni < 4; ni++) {
      const int dloc = ni * 16 + cc;
      const int dsub = dloc >> 5;
      const int chunk = (dloc & 31) >> 3, elem = dloc & 7;
      const int col = bn + wn + ni * 16 + cc;
      const float theta = __expf(-(float)(col & 31) * 0.2878231366242557f);
      const float sgn = (col & 1) ? 1.0f : -1.0f;
#pragma unroll
      for (int mi = 0; mi < 4; mi++) {
        const int lrow0 = wm + mi * 16 + quad * 4;
#pragma unroll
        for (int r = 0; r < 4; r++) {
          const float val = acc[mi][ni][r];
          const float pr = __shfl_xor(val, 1);
          float sv, cv;
          __sincosf(theta * (float)(bm + lrow0 + r), &sv, &cv);
          const int row = lrow0 + r;
          krh[dsub * 4096 + row * 32 + ((chunk ^ ((row >> 1) & 3)) << 3) + elem] =
              f2bf(val * cv + sgn * pr * sv);
        }
      }
    }
    __syncthreads();
    // stage wbT for both heads into As (8KB) / Bs (8KB)
    const int hg0 = (bn >> 6) & 15;
#pragma unroll
    for (int i = 0; i < 2; i++) {
      const int o = (i * 256 + t) * 16;
      const int row = o >> 6;
      const int dsub = row >> 6, e = row & 63;
      const int colb = swz_src_colb(o);
      gld16((const char*)wbT + (((size_t)hg0 * 4096 + e * 64 + dsub * 32) << 1) + colb,
            (char*)As + o);
      gld16((const char*)wbT + (((size_t)(hg0 + 1) * 4096 + e * 64 + dsub * 32) << 1) + colb,
            (char*)Bs + o);
    }
    __syncthreads();
    const int wmrow = (w >> 1) << 6;
    const u16* Bsel = h2 ? Bs : As;
    f32x4 acc2[4][4];
#pragma unroll
    for (int i = 0; i < 4; i++)
#pragma unroll
      for (int j = 0; j < 4; j++) acc2[i][j] = fzero;
#pragma unroll
    for (int dsub = 0; dsub < 2; dsub++) {
      bf16x8 bfr[4];
#pragma unroll
      for (int et = 0; et < 4; et++)
        bfr[et] = *(const bf16x8*)&Bsel[swz(dsub * 64 + et * 16 + cc, quad)];
#pragma unroll
      for (int mi = 0; mi < 4; mi++) {
        const bf16x8 af = *(const bf16x8*)&krh[dsub * 4096 + swz(wmrow + mi * 16 + cc, quad)];
#pragma unroll
        for (int et = 0; et < 4; et++)
          acc2[mi][et] = MFMA(af, bfr[et], acc2[mi][et]);
      }
    }
    u16* Ck = kth + (size_t)(hg0 + h2) * 2048 * 64;
#pragma unroll
    for (int mi = 0; mi < 4; mi++) {
      const int n0 = bm + wmrow + mi * 16 + quad * 4;
#pragma unroll
      for (int et = 0; et < 4; et++) {
        const int e = et * 16 + cc;
#pragma unroll
        for (int r = 0; r < 4; r++)
          Ck[(size_t)(n0 + r) * 64 + e] = f2bf(acc2[mi][et][r]);
      }
    }
  }
}

// ---------------------------------------------------------------------------
// Flash attention R12.  Grid 1024: h = (bid&7)|((bid>>8&1)<<3), qt =
// (bid>>3)&31, jh = bid>>9.  Each block: 64 q-rows x 8 j-tiles (its half).
// Additive no-max partials -> part[(qt*16+h)*2+jh] ([e64][q64] f32 linear)
// + lpart.  In-block structure identical to R10.  LDS 48KB, 3 blocks/CU.
// ---------------------------------------------------------------------------
__global__ __launch_bounds__(256, 3) void attn_kernel(
    const u16* __restrict__ qh, const u16* __restrict__ kth,
    const u16* __restrict__ vt, float* __restrict__ part,
    float* __restrict__ lpart) {
  __shared__ u16 Ks[2 * 128 * 32];   // 16KB; merge: O-half A [e64][q64] f32 swz
  __shared__ u16 Vs[4 * 64 * 32];    // 16KB; merge: O-half B
  __shared__ u16 Ps[4 * 64 * 32];    // 16KB; merge: l partials
  const int t = threadIdx.x;
  const int w = t >> 6, lane = t & 63, quad = lane >> 4, cc = lane & 15;
  const int bid = blockIdx.x;
  const int h = (bid & 7) | (((bid >> 8) & 1) << 3);  // XCD-aware head map
  const int qt = (bid >> 3) & 31;
  const int jh = bid >> 9;
  const int q0 = qt << 6;
  const size_t hq = (size_t)h * (2048 * 64);
  const f32x4 fzero = {0.f, 0.f, 0.f, 0.f};
  const int g4 = (cc >> 1) & 3;

  bf16x8 ones;
  {
    union { u16 u; __bf16 b; } one; one.u = 0x3F80;
#pragma unroll
    for (int i = 0; i < 8; i++) ones[i] = one.b;
  }

  // ---- stage Q (64x64) into Ks; hoist B-frags ----
#pragma unroll
  for (int i = 0; i < 2; i++) {
    const int o = (i * 256 + t) * 16;
    const int sub = o >> 12, row = (o >> 6) & 63, colb = swz_src_colb(o);
    gld16((const char*)qh + ((hq + (size_t)(q0 + row) * 64 + sub * 32) << 1) + colb,
          (char*)Ks + o);
  }
  __syncthreads();
  bf16x8 qf[4][2];
#pragma unroll
  for (int qn = 0; qn < 4; qn++)
#pragma unroll
    for (int ds = 0; ds < 2; ds++)
      qf[qn][ds] = *(const bf16x8*)&Ks[swz(ds * 64 + qn * 16 + cc, quad)];

  f32x4 oacc[4][4];
  f32x4 lacc[4];
#pragma unroll
  for (int mi = 0; mi < 4; mi++) {
    lacc[mi] = fzero;
#pragma unroll
    for (int et = 0; et < 4; et++) oacc[mi][et] = fzero;
  }

  u16* const psw = Ps + (w << 11);

  for (int jt = jh * 8; jt < jh * 8 + 8; jt++) {
    const int j0 = jt << 7;
    __syncthreads();
#pragma unroll
    for (int i = 0; i < 4; i++) {
      const int o = (i * 256 + t) * 16;
      const int colb = swz_src_colb(o);
      const int sub = o >> 13, row = (o >> 6) & 127;
      gld16((const char*)kth + ((hq + (size_t)(j0 + row) * 64 + sub * 32) << 1) + colb,
            (char*)Ks + o);
      const int vsub = o >> 12, vrow = (o >> 6) & 63;
      gld16((const char*)vt + ((hq + (size_t)vrow * 2048 + j0 + vsub * 32) << 1) + colb,
            (char*)Vs + o);
    }
    __syncthreads();

    // ---- S^T = K x Q^T; P = exp(S), packed uint2, 16B-chunk swizzle ----
#pragma unroll
    for (int jm = 0; jm < 2; jm++) {
      const bf16x8 kf0 = *(const bf16x8*)&Ks[swz(w * 32 + jm * 16 + cc, quad)];
      const bf16x8 kf1 = *(const bf16x8*)&Ks[swz(128 + w * 32 + jm * 16 + cc, quad)];
      const int c16 = ((jm << 1) + (quad >> 1)) ^ g4;
      const int coff = (c16 << 3) + ((quad & 1) << 2);
#pragma unroll
      for (int qn = 0; qn < 4; qn++) {
        f32x4 s = MFMA(kf0, qf[qn][0], fzero);
        s = MFMA(kf1, qf[qn][1], s);
        uint2 pk;
        pk.x = pk2bf(__expf(s[0]), __expf(s[1]));
        pk.y = pk2bf(__expf(s[2]), __expf(s[3]));
        *(uint2*)&psw[((qn * 16 + cc) << 5) + coff] = pk;
      }
    }

    // ---- O += P*V, l += P*1 ----
    bf16x8 vf[4];
#pragma unroll
    for (int et = 0; et < 4; et++)
      vf[et] = *(const bf16x8*)&Vs[swz(w * 64 + et * 16 + cc, quad)];
#pragma unroll
    for (int mi = 0; mi < 4; mi++) {
      const bf16x8 pa = *(const bf16x8*)&psw[swz(mi * 16 + cc, quad)];
      lacc[mi] = MFMA(pa, ones, lacc[mi]);
#pragma unroll
      for (int et = 0; et < 4; et++) oacc[mi][et] = MFMA(pa, vf[et], oacc[mi][et]);
    }
  }

  // ---- merge 4 wave-partials in LDS (additive) ----
  float* OA = (float*)Ks;
  float* OB = (float*)Vs;
  float* lP = (float*)Ps;
  __syncthreads();
  if (w >= 2) {
    float* dst = (w == 2) ? OA : OB;
#pragma unroll
    for (int mi = 0; mi < 4; mi++) {
#pragma unroll
      for (int et = 0; et < 4; et++) {
        const int ee = et * 16 + cc;
        *(f32x4*)&dst[mswz4(ee, mi * 4 + quad)] = oacc[mi][et];
      }
      if (cc == 0)
#pragma unroll
        for (int r = 0; r < 4; r++)
          lP[64 * w + mi * 16 + quad * 4 + r] = lacc[mi][r];
    }
  }
  __syncthreads();
  if (w < 2) {
    const float* src = (w == 0) ? OA : OB;
    const float* lsrc = &lP[64 * (w + 2)];
#pragma unroll
    for (int mi = 0; mi < 4; mi++) {
#pragma unroll
      for (int et = 0; et < 4; et++) {
        const int ee = et * 16 + cc;
        oacc[mi][et] += *(const f32x4*)&src[mswz4(ee, mi * 4 + quad)];
      }
#pragma unroll
      for (int r = 0; r < 4; r++)
        lacc[mi][r] += lsrc[mi * 16 + quad * 4 + r];
    }
  }
  __syncthreads();
  if (w < 2) {
    float* dst = (w == 0) ? OA : OB;
#pragma unroll
    for (int mi = 0; mi < 4; mi++) {
#pragma unroll
      for (int et = 0; et < 4; et++) {
        const int ee = et * 16 + cc;
        *(f32x4*)&dst[mswz4(ee, mi * 4 + quad)] = oacc[mi][et];
      }
      if (cc == 0)
#pragma unroll
        for (int r = 0; r < 4; r++)
          lP[64 * w + mi * 16 + quad * 4 + r] = lacc[mi][r];
    }
  }
  __syncthreads();

  // ---- export block partial: part[pi2] = [e64][q64] f32 linear + l ----
  {
    const int pi2 = ((qt << 4) | h) * 2 + jh;
    float* pdst = part + ((size_t)pi2 << 12);
    const int e = t >> 2;
#pragma unroll
    for (int i = 0; i < 4; i++) {
      const int qc = (t & 3) * 4 + i;                  // 16B q-chunk index
      const int off = ((qc ^ (e & 15)) << 2);          // mswz descramble
      const f32x4 a = *(const f32x4*)&OA[e * 64 + off];
      const f32x4 b = *(const f32x4*)&OB[e * 64 + off];
      *(f32x4*)&pdst[e * 64 + qc * 4] = a + b;
    }
    if (t < 64) lpart[pi2 * 64 + t] = lP[t] + lP[64 + t];
  }
}

// ---------------------------------------------------------------------------
// merge: sum the two j-half partials, normalize by l, write aout bf16.
// Grid 512 (= qt*16+h pairs), 256 threads.  LDS ~9.4KB.
// R12 fix: final writeout loops BOTH chunk halves (c, c+4) -> e in [0,64).
// ---------------------------------------------------------------------------
__global__ __launch_bounds__(256) void merge_kernel(
    const float* __restrict__ part, const float* __restrict__ lpart,
    u16* __restrict__ aout) {
  __shared__ float linv[64];
  __shared__ u16 tile[64 * 72];   // [q][e], stride 72 u16 (16B-aligned rows)
  const int pi = blockIdx.x, t = threadIdx.x;
  const int h = pi & 15, qt = pi >> 4, q0 = qt << 6;
  const float* pa = part + ((size_t)(pi * 2 + 0) << 12);
  const float* pb = part + ((size_t)(pi * 2 + 1) << 12);
  if (t < 64)
    linv[t] = 1.0f / (lpart[(pi * 2) * 64 + t] + lpart[(pi * 2 + 1) * 64 + t]);
  __syncthreads();
  const int e = t >> 2;
#pragma unroll
  for (int i = 0; i < 4; i++) {
    const int q = (t & 3) * 16 + i * 4;
    const f32x4 a = *(const f32x4*)&pa[t * 16 + i * 4];
    const f32x4 b = *(const f32x4*)&pb[t * 16 + i * 4];
#pragma unroll
    for (int r = 0; r < 4; r++)
      tile[(q + r) * 72 + e] = f2bf((a[r] + b[r]) * linv[q + r]);
  }
  __syncthreads();
  const int row = t & 63;
#pragma unroll
  for (int half = 0; half < 2; half++) {
    const int c = (t >> 6) + half * 4;   // 8-u16 chunk of the 64-e row
    *(uint4*)&aout[(size_t)(q0 + row) * 1024 + h * 64 + c * 8] =
        *(const uint4*)&tile[row * 72 + c * 8];
  }
}

// ---------------------------------------------------------------------------
// out = aout(2048x1024 bf16) @ Wo -> f32.  64x64 tiles, BK=64, 512 blocks.
// ---------------------------------------------------------------------------
__global__ __launch_bounds__(256, 2) void gemm64_bt_f32(
    const u16* __restrict__ A, const u16* __restrict__ B, float* __restrict__ C,
    int M, int N, int K) {
  __shared__ u16 As[2 * 64 * 32];   // 8KB: [ksub][row 64][k 32] swz
  __shared__ u16 Bs[2 * 64 * 32];
  const int t = threadIdx.x;
  const int w = t >> 6, lane = t & 63, quad = lane >> 4, cc = lane & 15;
  const int bm = blockIdx.y << 6, bn = blockIdx.x << 6;
  const int wm = (w >> 1) << 5, wn = (w & 1) << 5;
  const f32x4 fzero = {0.f, 0.f, 0.f, 0.f};
  f32x4 acc[2][2];
#pragma unroll
  for (int i = 0; i < 2; i++)
#pragma unroll
    for (int j = 0; j < 2; j++) acc[i][j] = fzero;

  const char* gA = (const char*)A;
  const char* gB = (const char*)B;
  for (int k0 = 0; k0 < K; k0 += 64) {
    __syncthreads();
#pragma unroll
    for (int i = 0; i < 2; i++) {
      const int o = (i * 256 + t) * 16;
      const int sub = o >> 12, row = (o >> 6) & 63, colb = swz_src_colb(o);
      gld16(gA + (((size_t)(bm + row) * K + k0 + sub * 32) << 1) + colb, (char*)As + o);
      gld16(gB + (((size_t)(bn + row) * K + k0 + sub * 32) << 1) + colb, (char*)Bs + o);
    }
    __syncthreads();
#pragma unroll
    for (int ks = 0; ks < 2; ks++) {
      bf16x8 af[2], bfr[2];
#pragma unroll
      for (int mi = 0; mi < 2; mi++)
        af[mi] = *(const bf16x8*)&As[ks * 2048 + swz(wm + mi * 16 + cc, quad)];
#pragma unroll
      for (int ni = 0; ni < 2; ni++)
        bfr[ni] = *(const bf16x8*)&Bs[ks * 2048 + swz(wn + ni * 16 + cc, quad)];
#pragma unroll
      for (int mi = 0; mi < 2; mi++)
#pragma unroll
        for (int ni = 0; ni < 2; ni++)
          acc[mi][ni] = MFMA(af[mi], bfr[ni], acc[mi][ni]);
    }
  }
#pragma unroll
  for (int mi = 0; mi < 2; mi++) {
    const int row = bm + wm + mi * 16 + quad * 4;
#pragma unroll
    for (int ni = 0; ni < 2; ni++) {
      const int col = bn + wn + ni * 16 + cc;
#pragma unroll
      for (int r = 0; r < 4; r++) C[(size_t)(row + r) * N + col] = acc[mi][ni][r];
    }
  }
}

// ---------------------------------------------------------------------------
// host side
// ---------------------------------------------------------------------------
extern "C" void kernel_launch(void* const* d_in, const int* in_sizes, int n_in,
                              void* d_out, int out_size, void* d_ws, size_t ws_size,
                              hipStream_t stream) {
  (void)in_sizes; (void)n_in; (void)out_size; (void)ws_size;
  const float* x     = (const float*)d_in[0];
  const float* gamma = (const float*)d_in[1];
  const float* Wq    = (const float*)d_in[2];
  const float* Wkv   = (const float*)d_in[3];
  const float* Wb    = (const float*)d_in[4];
  const float* Wo    = (const float*)d_in[5];
  float* out = (float*)d_out;
  char* ws = (char*)d_ws;

  const size_t OFF_XN    = 0;           // 4 MB
  const size_t OFF_WQKVT = 4194304;     // 6 MB
  const size_t OFF_WOT   = 10485760;    // 2 MB
  const size_t OFF_WBT   = 12582912;    // 128 KB
  const size_t OFF_QH    = 12713984;    // 4 MB
  const size_t OFF_KTH   = 16908288;    // 4 MB
  const size_t OFF_VT    = 21102592;    // 4 MB
  const size_t OFF_AOUT  = 25296896;    // 4 MB
  const size_t OFF_PART  = 29491200;    // 16 MB (1024 x 4096 f32)
  const size_t OFF_LPART = 46268416;    // 256 KB -> end ~46.5 MB

  u16*   xn    = (u16*)(ws + OFF_XN);
  u16*   wqkvT = (u16*)(ws + OFF_WQKVT);
  u16*   woT   = (u16*)(ws + OFF_WOT);
  u16*   wbT   = (u16*)(ws + OFF_WBT);
  u16*   qh    = (u16*)(ws + OFF_QH);
  u16*   kth   = (u16*)(ws + OFF_KTH);
  u16*   vt    = (u16*)(ws + OFF_VT);
  u16*   aout  = (u16*)(ws + OFF_AOUT);
  float* part  = (float*)(ws + OFF_PART);
  float* lpart = (float*)(ws + OFF_LPART);

  prep_kernel<<<6208, 256, 0, stream>>>(x, gamma, Wq, Wkv, Wo, Wb,
                                        xn, wqkvT, woT, wbT);
  gemm_qkv<<<dim3(24, 16), 256, 0, stream>>>(xn, wqkvT, wbT, qh, kth, vt);
  attn_kernel<<<1024, 256, 0, stream>>>(qh, kth, vt, part, lpart);
  merge_kernel<<<512, 256, 0, stream>>>(part, lpart, aout);
  gemm64_bt_f32<<<dim3(16, 32), 256, 0, stream>>>(aout, woT, out, 2048, 1024, 1024);
}

// Round 13
// 146.468 us; speedup vs baseline: 1.0721x; 1.0721x over previous
//
#include <hip/hip_runtime.h>
#include <hip/hip_bf16.h>

// ---------------------------------------------------------------------------
// Fused: LN -> qkv GEMM (+RoPE/bilinear/v-transpose epilogues) -> flash attn
//        -> out GEMM.  B=1, N=2048, DIM=1024, HEADS=16, DHEAD=64.
// R13 = best-of-all recombination:
//   attn + gemm64: R10 verbatim (best measured total, 150.96 us)
//   gemm_qkv: BK=64 (R12-proven; 16 k-iters = half the barrier drains,
//             occupancy unchanged at 2 blocks/CU)
//   prep: 64x64 transpose tiles (6208 -> 3088 blocks, 4x work per block)
// 4 launches: prep, gemm_qkv, attn, gemm64.
// Journal: R9 q-split / R11-12 j-split both neutral-to-negative -- attn's
// ~40us is the 2-barrier K-loop vmcnt(0) plateau (m97-family); stop fighting
// it with overhead-bearing splits.
// ---------------------------------------------------------------------------

typedef unsigned short u16;
typedef __attribute__((ext_vector_type(4))) float f32x4;
typedef __attribute__((ext_vector_type(8))) __bf16 bf16x8;

struct alignas(8) US4 { u16 x, y, z, w; };

__device__ __forceinline__ u16 f2bf(float f) {
  union { float f; unsigned u; } v; v.f = f;
  unsigned r = v.u + 0x7FFFu + ((v.u >> 16) & 1u);   // RNE
  return (u16)(r >> 16);
}
// packed f32 pair -> bf16x2 (v_cvt_pk_bf16_f32, RNE -- bit-identical to f2bf)
__device__ __forceinline__ unsigned pk2bf(float a, float b) {
  float2 f; f.x = a; f.y = b;
  __hip_bfloat162 h = __float22bfloat162_rn(f);
  union { __hip_bfloat162 h; unsigned u; } v; v.h = h;
  return v.u;
}

typedef void GVOID __attribute__((address_space(1)));
typedef void LVOID __attribute__((address_space(3)));

#if defined(__has_builtin)
#if __has_builtin(__builtin_amdgcn_global_load_lds)
#define HAS_GLD_LDS 1
#endif
#endif

__device__ __forceinline__ void gld16(const void* g, void* l) {
#ifdef HAS_GLD_LDS
  __builtin_amdgcn_global_load_lds((GVOID*)(void*)g, (LVOID*)l, 16, 0, 0);
#else
  struct alignas(16) U4 { unsigned a, b, c, d; };
  *(U4*)l = *(const U4*)g;
#endif
}

__device__ __forceinline__ f32x4 MFMA(bf16x8 a, bf16x8 b, f32x4 c) {
  return __builtin_amdgcn_mfma_f32_16x16x32_bf16(a, b, c, 0, 0, 0);
}

// LDS swizzle for 64B-row tiles (32 u16/row, 4 x 16B chunks)
__device__ __forceinline__ int swz(int r, int q) {   // u16 index
  return r * 32 + ((q ^ ((r >> 1) & 3)) << 3);
}
__device__ __forceinline__ int swz_src_colb(int o) { // byte offset in 64B row
  const int r = o >> 6;
  return ((((o >> 4) & 3) ^ ((r >> 1) & 3)) << 4);
}
// merge-phase f32 [64][64] arrays: 16B chunk c of row ee at chunk c^(ee&15)
__device__ __forceinline__ int mswz4(int ee, int c) {  // f32 idx, 16B chunk
  return ee * 64 + ((c ^ (ee & 15)) << 2);
}
__device__ __forceinline__ int mswz1(int ee, int q) {  // f32 idx, scalar q
  return ee * 64 + ((((q >> 2) ^ (ee & 15)) << 2) | (q & 3));
}

// ---------------------------------------------------------------------------
// prep: weight transposes (+bf16 cast, 64x64 tiles) and LayerNorm.
// grid: [0,256) Wq | [256,768) Wkv | [768,1024) Wo | [1024,1040) Wb |
//       [1040,3088) LN rows.
// ---------------------------------------------------------------------------
__global__ __launch_bounds__(256) void prep_kernel(
    const float* __restrict__ x, const float* __restrict__ gamma,
    const float* __restrict__ Wq, const float* __restrict__ Wkv,
    const float* __restrict__ Wo, const float* __restrict__ Wb,
    u16* __restrict__ xn, u16* __restrict__ wqkvT, u16* __restrict__ woT,
    u16* __restrict__ wbT) {
  __shared__ __align__(16) float smem[64 * 65];   // 16.6KB
  const int bid = blockIdx.x, t = threadIdx.x;
  if (bid < 1040) {
    const float* src; u16* dst; int C, R, bx, by;
    if (bid < 256)      { src = Wq;  dst = wqkvT; R = 1024; C = 1024; bx = bid & 15; by = bid >> 4; }
    else if (bid < 768) { int i = bid - 256; src = Wkv; dst = wqkvT + 1024 * 1024; R = 1024; C = 2048; bx = i & 31; by = i >> 5; }
    else if (bid < 1024){ int i = bid - 768; src = Wo;  dst = woT; R = 1024; C = 1024; bx = i & 15; by = i >> 4; }
    else { int h = bid - 1024; src = Wb + (size_t)h * 4096; dst = wbT + (size_t)h * 4096; R = 64; C = 64; bx = 0; by = 0; }
    float (*tile)[65] = (float(*)[65])smem;
    const int c0 = bx * 64, r0 = by * 64;
    const int tx = t & 63, ty = t >> 6;  // 64 x 4
#pragma unroll
    for (int i = 0; i < 16; i++)
      tile[ty + i * 4][tx] = src[(size_t)(r0 + ty + i * 4) * C + c0 + tx];
    __syncthreads();
#pragma unroll
    for (int i = 0; i < 16; i++)
      dst[(size_t)(c0 + ty + i * 4) * R + r0 + tx] = f2bf(tile[tx][ty + i * 4]);
  } else {
    const int n = bid - 1040;
    const int w = t >> 6, lane = t & 63;
    const float4 v = *(const float4*)&x[(size_t)n * 1024 + t * 4];
    float s = v.x + v.y + v.z + v.w;
    float q = v.x * v.x + v.y * v.y + v.z * v.z + v.w * v.w;
#pragma unroll
    for (int off = 32; off; off >>= 1) {
      s += __shfl_down(s, off);
      q += __shfl_down(q, off);
    }
    if (lane == 0) { smem[w] = s; smem[4 + w] = q; }
    __syncthreads();
    s = smem[0] + smem[1] + smem[2] + smem[3];
    q = smem[4] + smem[5] + smem[6] + smem[7];
    const float mean = s * (1.0f / 1024.0f);
    const float var = q * (1.0f / 1024.0f) - mean * mean;
    const float inv = rsqrtf(var + 1e-5f);
    const float4 g = *(const float4*)&gamma[t * 4];
    US4 o;
    o.x = f2bf((v.x - mean) * inv * g.x);
    o.y = f2bf((v.y - mean) * inv * g.y);
    o.z = f2bf((v.z - mean) * inv * g.z);
    o.w = f2bf((v.w - mean) * inv * g.w);
    *(US4*)&xn[(size_t)n * 1024 + t * 4] = o;
  }
}

// ---------------------------------------------------------------------------
// qkv GEMM, 128x128 tile, BK=64, grid (24,16).  Epilogues by region:
//   q: rope*0.125 -> qh | k: rope -> LDS -> @wbT -> kth | v: cast -> vt.
// LDS: As 16K + Bs 16K + krs 32K = 64KB -> 2 blocks/CU.
// ---------------------------------------------------------------------------
__global__ __launch_bounds__(256, 2) void gemm_qkv(
    const u16* __restrict__ A, const u16* __restrict__ B,
    const u16* __restrict__ wbT, u16* __restrict__ qh,
    u16* __restrict__ kth, u16* __restrict__ vt) {
  __shared__ u16 As[2 * 128 * 32];   // 16KB [ksub][row128][k32] swz
  __shared__ u16 Bs[2 * 128 * 32];   // 16KB
  __shared__ u16 krs[2 * 8192];      // 32KB: [head2][dsub2][row128][d32] swz
  const int K = 1024;
  const int t = threadIdx.x;
  const int w = t >> 6, lane = t & 63, quad = lane >> 4, cc = lane & 15;
  const int bm = blockIdx.y << 7, bn = blockIdx.x << 7;
  const int wm = (w >> 1) << 6, wn = (w & 1) << 6;
  const f32x4 fzero = {0.f, 0.f, 0.f, 0.f};
  f32x4 acc[4][4];
#pragma unroll
  for (int i = 0; i < 4; i++)
#pragma unroll
    for (int j = 0; j < 4; j++) acc[i][j] = fzero;

  const char* gA = (const char*)A;
  const char* gB = (const char*)B;
  for (int k0 = 0; k0 < K; k0 += 64) {
    __syncthreads();
#pragma unroll
    for (int i = 0; i < 4; i++) {
      const int o = (i * 256 + t) * 16;
      const int sub = o >> 13, row = (o >> 6) & 127, colb = swz_src_colb(o);
      gld16(gA + (((size_t)(bm + row) * K + k0 + sub * 32) << 1) + colb, (char*)As + o);
      gld16(gB + (((size_t)(bn + row) * K + k0 + sub * 32) << 1) + colb, (char*)Bs + o);
    }
    __syncthreads();
#pragma unroll
    for (int ks = 0; ks < 2; ks++) {
      bf16x8 af[4], bfr[4];
#pragma unroll
      for (int mi = 0; mi < 4; mi++)
        af[mi] = *(const bf16x8*)&As[ks * 4096 + swz(wm + mi * 16 + cc, quad)];
#pragma unroll
      for (int ni = 0; ni < 4; ni++)
        bfr[ni] = *(const bf16x8*)&Bs[ks * 4096 + swz(wn + ni * 16 + cc, quad)];
#pragma unroll
      for (int mi = 0; mi < 4; mi++)
#pragma unroll
        for (int ni = 0; ni < 4; ni++)
          acc[mi][ni] = MFMA(af[mi], bfr[ni], acc[mi][ni]);
    }
  }

  const int region = blockIdx.x >> 3;  // 0=q, 1=k, 2=v (uniform per block)
  if (region == 0) {
    // ---- q: rope * 0.125 -> qh ----
#pragma unroll
    for (int ni = 0; ni < 4; ni++) {
      const int col = bn + wn + ni * 16 + cc;
      const int h = (col >> 6) & 15, d = col & 63;
      const float theta = __expf(-(float)(col & 31) * 0.2878231366242557f);
      const float sgn = (col & 1) ? 1.0f : -1.0f;
#pragma unroll
      for (int mi = 0; mi < 4; mi++) {
        const int row0 = bm + wm + mi * 16 + quad * 4;
#pragma unroll
        for (int r = 0; r < 4; r++) {
          const float val = acc[mi][ni][r];
          const float pr = __shfl_xor(val, 1);
          float sv, cv;
          __sincosf(theta * (float)(row0 + r), &sv, &cv);
          qh[((size_t)h * 2048 + row0 + r) * 64 + d] =
              f2bf((val * cv + sgn * pr * sv) * 0.125f);
        }
      }
    }
  } else if (region == 2) {
    // ---- v: direct transpose write vt[h][d][n] ----
#pragma unroll
    for (int ni = 0; ni < 4; ni++) {
      const int col = bn + wn + ni * 16 + cc;
      const int h = (col >> 6) & 15, d = col & 63;
      u16* base = vt + ((size_t)h * 64 + d) * 2048;
#pragma unroll
      for (int mi = 0; mi < 4; mi++) {
        const int row0 = bm + wm + mi * 16 + quad * 4;
        uint2 pk;
        pk.x = pk2bf(acc[mi][ni][0], acc[mi][ni][1]);
        pk.y = pk2bf(acc[mi][ni][2], acc[mi][ni][3]);
        *(uint2*)&base[row0] = pk;
      }
    }
  } else {
    // ---- k: rope -> krs (A-layout, swz) ----
    const int h2 = w & 1;
    u16* krh = krs + h2 * 8192;
#pragma unroll
    for (int ni = 0; ni < 4; ni++) {
      const int dloc = ni * 16 + cc;
      const int dsub = dloc >> 5;
      const int chunk = (dloc & 31) >> 3, elem = dloc & 7;
      const int col = bn + wn + ni * 16 + cc;
      const float theta = __expf(-(float)(col & 31) * 0.2878231366242557f);
      const float sgn = (col & 1) ? 1.0f : -1.0f;
#pragma unroll
      for (int mi = 0; mi < 4; mi++) {
        const int lrow0 = wm + mi * 16 + quad * 4;
#pragma unroll
        for (int r = 0; r < 4; r++) {
          const float val = acc[mi][ni][r];
          const float pr = __shfl_xor(val, 1);
          float sv, cv;
          __sincosf(theta * (float)(bm + lrow0 + r), &sv, &cv);
          const int row = lrow0 + r;
          krh[dsub * 4096 + row * 32 + ((chunk ^ ((row >> 1) & 3)) << 3) + elem] =
              f2bf(val * cv + sgn * pr * sv);
        }
      }
    }
    __syncthreads();
    // stage wbT for both heads into As (8KB) / Bs (8KB)
    const int hg0 = (bn >> 6) & 15;
#pragma unroll
    for (int i = 0; i < 2; i++) {
      const int o = (i * 256 + t) * 16;
      const int row = o >> 6;
      const int dsub = row >> 6, e = row & 63;
      const int colb = swz_src_colb(o);
      gld16((const char*)wbT + (((size_t)hg0 * 4096 + e * 64 + dsub * 32) << 1) + colb,
            (char*)As + o);
      gld16((const char*)wbT + (((size_t)(hg0 + 1) * 4096 + e * 64 + dsub * 32) << 1) + colb,
            (char*)Bs + o);
    }
    __syncthreads();
    const int wmrow = (w >> 1) << 6;
    const u16* Bsel = h2 ? Bs : As;
    f32x4 acc2[4][4];
#pragma unroll
    for (int i = 0; i < 4; i++)
#pragma unroll
      for (int j = 0; j < 4; j++) acc2[i][j] = fzero;
#pragma unroll
    for (int dsub = 0; dsub < 2; dsub++) {
      bf16x8 bfr[4];
#pragma unroll
      for (int et = 0; et < 4; et++)
        bfr[et] = *(const bf16x8*)&Bsel[swz(dsub * 64 + et * 16 + cc, quad)];
#pragma unroll
      for (int mi = 0; mi < 4; mi++) {
        const bf16x8 af = *(const bf16x8*)&krh[dsub * 4096 + swz(wmrow + mi * 16 + cc, quad)];
#pragma unroll
        for (int et = 0; et < 4; et++)
          acc2[mi][et] = MFMA(af, bfr[et], acc2[mi][et]);
      }
    }
    u16* Ck = kth + (size_t)(hg0 + h2) * 2048 * 64;
#pragma unroll
    for (int mi = 0; mi < 4; mi++) {
      const int n0 = bm + wmrow + mi * 16 + quad * 4;
#pragma unroll
      for (int et = 0; et < 4; et++) {
        const int e = et * 16 + cc;
#pragma unroll
        for (int r = 0; r < 4; r++)
          Ck[(size_t)(n0 + r) * 64 + e] = f2bf(acc2[mi][et][r]);
      }
    }
  }
}

// ---------------------------------------------------------------------------
// Flash attention (R10 verbatim).  One block = one head x 64 q-rows; grid
// 512.  Wave w owns j-stripe [w*32,w*32+32), all 64 q-rows.  No-max softmax;
// l via MFMA-with-ones; S^T so P writes are packed uint2 (16B-chunk swz);
// P read = plain b128.  Merge O-exchange uses mswz.  LDS 48KB.
// ---------------------------------------------------------------------------
__global__ __launch_bounds__(256, 2) void attn_kernel(
    const u16* __restrict__ qh, const u16* __restrict__ kth,
    const u16* __restrict__ vt, u16* __restrict__ aout) {
  __shared__ u16 Ks[2 * 128 * 32];   // 16KB; merge: O-half A [e64][q64] f32 swz
  __shared__ u16 Vs[4 * 64 * 32];    // 16KB; merge: O-half B
  __shared__ u16 Ps[4 * 64 * 32];    // 16KB; merge: l partials
  const int t = threadIdx.x;
  const int w = t >> 6, lane = t & 63, quad = lane >> 4, cc = lane & 15;
  const int bid = blockIdx.x;
  const int h = (bid & 7) + ((bid >> 8) << 3);   // XCD-aware head mapping
  const int q0 = ((bid >> 3) & 31) << 6;
  const size_t hq = (size_t)h * (2048 * 64);
  const f32x4 fzero = {0.f, 0.f, 0.f, 0.f};
  const int g4 = (cc >> 1) & 3;      // = (row>>1)&3 for row = X*16+cc

  bf16x8 ones;
  {
    union { u16 u; __bf16 b; } one; one.u = 0x3F80;  // bf16 1.0
#pragma unroll
    for (int i = 0; i < 8; i++) ones[i] = one.b;
  }

  // ---- stage Q (64x64) into Ks; hoist B-frags ----
#pragma unroll
  for (int i = 0; i < 2; i++) {
    const int o = (i * 256 + t) * 16;
    const int sub = o >> 12, row = (o >> 6) & 63, colb = swz_src_colb(o);
    gld16((const char*)qh + ((hq + (size_t)(q0 + row) * 64 + sub * 32) << 1) + colb,
          (char*)Ks + o);
  }
  __syncthreads();
  bf16x8 qf[4][2];
#pragma unroll
  for (int qn = 0; qn < 4; qn++)
#pragma unroll
    for (int ds = 0; ds < 2; ds++)
      qf[qn][ds] = *(const bf16x8*)&Ks[swz(ds * 64 + qn * 16 + cc, quad)];

  f32x4 oacc[4][4];
  f32x4 lacc[4];
#pragma unroll
  for (int mi = 0; mi < 4; mi++) {
    lacc[mi] = fzero;
#pragma unroll
    for (int et = 0; et < 4; et++) oacc[mi][et] = fzero;
  }

  u16* const psw = Ps + (w << 11);   // this wave's 4KB P tile (2048 u16)

  for (int jt = 0; jt < 16; jt++) {
    const int j0 = jt << 7;
    __syncthreads();
#pragma unroll
    for (int i = 0; i < 4; i++) {
      const int o = (i * 256 + t) * 16;
      const int colb = swz_src_colb(o);
      const int sub = o >> 13, row = (o >> 6) & 127;
      gld16((const char*)kth + ((hq + (size_t)(j0 + row) * 64 + sub * 32) << 1) + colb,
            (char*)Ks + o);
      const int vsub = o >> 12, vrow = (o >> 6) & 63;
      gld16((const char*)vt + ((hq + (size_t)vrow * 2048 + j0 + vsub * 32) << 1) + colb,
            (char*)Vs + o);
    }
    __syncthreads();

    // ---- S^T = K x Q^T; P = exp(S), packed uint2, 16B-chunk swizzle ----
#pragma unroll
    for (int jm = 0; jm < 2; jm++) {
      const bf16x8 kf0 = *(const bf16x8*)&Ks[swz(w * 32 + jm * 16 + cc, quad)];
      const bf16x8 kf1 = *(const bf16x8*)&Ks[swz(128 + w * 32 + jm * 16 + cc, quad)];
      const int c16 = ((jm << 1) + (quad >> 1)) ^ g4;    // phys 16B chunk
      const int coff = (c16 << 3) + ((quad & 1) << 2);   // u16 offset in row
#pragma unroll
      for (int qn = 0; qn < 4; qn++) {
        f32x4 s = MFMA(kf0, qf[qn][0], fzero);
        s = MFMA(kf1, qf[qn][1], s);
        uint2 pk;
        pk.x = pk2bf(__expf(s[0]), __expf(s[1]));
        pk.y = pk2bf(__expf(s[2]), __expf(s[3]));
        *(uint2*)&psw[((qn * 16 + cc) << 5) + coff] = pk;
      }
    }

    // ---- O += P*V, l += P*1 (same-wave DS ops; no barrier) ----
    bf16x8 vf[4];
#pragma unroll
    for (int et = 0; et < 4; et++)
      vf[et] = *(const bf16x8*)&Vs[swz(w * 64 + et * 16 + cc, quad)];
#pragma unroll
    for (int mi = 0; mi < 4; mi++) {
      const bf16x8 pa = *(const bf16x8*)&psw[swz(mi * 16 + cc, quad)];
      lacc[mi] = MFMA(pa, ones, lacc[mi]);
#pragma unroll
      for (int et = 0; et < 4; et++) oacc[mi][et] = MFMA(pa, vf[et], oacc[mi][et]);
    }
  }

  // ---- merge the 4 wave-partials (additive: no-max softmax) ----
  float* OA = (float*)Ks;
  float* OB = (float*)Vs;
  float* lP = (float*)Ps;   // [0,64) lA | [64,128) lB | [128,192) l2 | [192,256) l3
  __syncthreads();
  if (w >= 2) {
    float* dst = (w == 2) ? OA : OB;
#pragma unroll
    for (int mi = 0; mi < 4; mi++) {
#pragma unroll
      for (int et = 0; et < 4; et++) {
        const int ee = et * 16 + cc;
        *(f32x4*)&dst[mswz4(ee, mi * 4 + quad)] = oacc[mi][et];
      }
      if (cc == 0)
#pragma unroll
        for (int r = 0; r < 4; r++)
          lP[64 * w + mi * 16 + quad * 4 + r] = lacc[mi][r];
    }
  }
  __syncthreads();
  if (w < 2) {
    const float* src = (w == 0) ? OA : OB;
    const float* lsrc = &lP[64 * (w + 2)];
#pragma unroll
    for (int mi = 0; mi < 4; mi++) {
#pragma unroll
      for (int et = 0; et < 4; et++) {
        const int ee = et * 16 + cc;
        oacc[mi][et] += *(const f32x4*)&src[mswz4(ee, mi * 4 + quad)];
      }
#pragma unroll
      for (int r = 0; r < 4; r++)
        lacc[mi][r] += lsrc[mi * 16 + quad * 4 + r];
    }
  }
  __syncthreads();
  if (w < 2) {
    float* dst = (w == 0) ? OA : OB;
#pragma unroll
    for (int mi = 0; mi < 4; mi++) {
#pragma unroll
      for (int et = 0; et < 4; et++) {
        const int ee = et * 16 + cc;
        *(f32x4*)&dst[mswz4(ee, mi * 4 + quad)] = oacc[mi][et];
      }
      if (cc == 0)
#pragma unroll
        for (int r = 0; r < 4; r++)
          lP[64 * w + mi * 16 + quad * 4 + r] = lacc[mi][r];
    }
  }
  __syncthreads();
  {
    const int q = lane;
    const float linv = 1.0f / (lP[q] + lP[64 + q]);
    unsigned obuf[8];
#pragma unroll
    for (int e = 0; e < 8; e++) {
      const int e0 = w * 16 + e * 2, e1 = e0 + 1;
      obuf[e] = pk2bf((OA[mswz1(e0, q)] + OB[mswz1(e0, q)]) * linv,
                      (OA[mswz1(e1, q)] + OB[mswz1(e1, q)]) * linv);
    }
    uint4* dst = (uint4*)&aout[(size_t)(q0 + q) * 1024 + h * 64 + w * 16];
    dst[0] = *(uint4*)&obuf[0];
    dst[1] = *(uint4*)&obuf[4];
  }
}

// ---------------------------------------------------------------------------
// out = aout(2048x1024 bf16) @ Wo -> f32.  64x64 tiles, BK=64, 512 blocks.
// ---------------------------------------------------------------------------
__global__ __launch_bounds__(256, 2) void gemm64_bt_f32(
    const u16* __restrict__ A, const u16* __restrict__ B, float* __restrict__ C,
    int M, int N, int K) {
  __shared__ u16 As[2 * 64 * 32];   // 8KB: [ksub][row 64][k 32] swz
  __shared__ u16 Bs[2 * 64 * 32];
  const int t = threadIdx.x;
  const int w = t >> 6, lane = t & 63, quad = lane >> 4, cc = lane & 15;
  const int bm = blockIdx.y << 6, bn = blockIdx.x << 6;
  const int wm = (w >> 1) << 5, wn = (w & 1) << 5;
  const f32x4 fzero = {0.f, 0.f, 0.f, 0.f};
  f32x4 acc[2][2];
#pragma unroll
  for (int i = 0; i < 2; i++)
#pragma unroll
    for (int j = 0; j < 2; j++) acc[i][j] = fzero;

  const char* gA = (const char*)A;
  const char* gB = (const char*)B;
  for (int k0 = 0; k0 < K; k0 += 64) {
    __syncthreads();
#pragma unroll
    for (int i = 0; i < 2; i++) {
      const int o = (i * 256 + t) * 16;
      const int sub = o >> 12, row = (o >> 6) & 63, colb = swz_src_colb(o);
      gld16(gA + (((size_t)(bm + row) * K + k0 + sub * 32) << 1) + colb, (char*)As + o);
      gld16(gB + (((size_t)(bn + row) * K + k0 + sub * 32) << 1) + colb, (char*)Bs + o);
    }
    __syncthreads();
#pragma unroll
    for (int ks = 0; ks < 2; ks++) {
      bf16x8 af[2], bfr[2];
#pragma unroll
      for (int mi = 0; mi < 2; mi++)
        af[mi] = *(const bf16x8*)&As[ks * 2048 + swz(wm + mi * 16 + cc, quad)];
#pragma unroll
      for (int ni = 0; ni < 2; ni++)
        bfr[ni] = *(const bf16x8*)&Bs[ks * 2048 + swz(wn + ni * 16 + cc, quad)];
#pragma unroll
      for (int mi = 0; mi < 2; mi++)
#pragma unroll
        for (int ni = 0; ni < 2; ni++)
          acc[mi][ni] = MFMA(af[mi], bfr[ni], acc[mi][ni]);
    }
  }
#pragma unroll
  for (int mi = 0; mi < 2; mi++) {
    const int row = bm + wm + mi * 16 + quad * 4;
#pragma unroll
    for (int ni = 0; ni < 2; ni++) {
      const int col = bn + wn + ni * 16 + cc;
#pragma unroll
      for (int r = 0; r < 4; r++) C[(size_t)(row + r) * N + col] = acc[mi][ni][r];
    }
  }
}

// ---------------------------------------------------------------------------
// host side
// ---------------------------------------------------------------------------
extern "C" void kernel_launch(void* const* d_in, const int* in_sizes, int n_in,
                              void* d_out, int out_size, void* d_ws, size_t ws_size,
                              hipStream_t stream) {
  (void)in_sizes; (void)n_in; (void)out_size; (void)ws_size;
  const float* x     = (const float*)d_in[0];
  const float* gamma = (const float*)d_in[1];
  const float* Wq    = (const float*)d_in[2];
  const float* Wkv   = (const float*)d_in[3];
  const float* Wb    = (const float*)d_in[4];
  const float* Wo    = (const float*)d_in[5];
  float* out = (float*)d_out;
  char* ws = (char*)d_ws;

  const size_t OFF_XN    = 0;           // 4 MB
  const size_t OFF_WQKVT = 4194304;     // 6 MB
  const size_t OFF_WOT   = 10485760;    // 2 MB
  const size_t OFF_WBT   = 12582912;    // 128 KB
  const size_t OFF_QH    = 12713984;    // 4 MB
  const size_t OFF_KTH   = 16908288;    // 4 MB
  const size_t OFF_VT    = 21102592;    // 4 MB
  const size_t OFF_AOUT  = 25296896;    // 4 MB -> end ~29.5 MB

  u16* xn    = (u16*)(ws + OFF_XN);
  u16* wqkvT = (u16*)(ws + OFF_WQKVT);
  u16* woT   = (u16*)(ws + OFF_WOT);
  u16* wbT   = (u16*)(ws + OFF_WBT);
  u16* qh    = (u16*)(ws + OFF_QH);
  u16* kth   = (u16*)(ws + OFF_KTH);
  u16* vt    = (u16*)(ws + OFF_VT);
  u16* aout  = (u16*)(ws + OFF_AOUT);

  prep_kernel<<<3088, 256, 0, stream>>>(x, gamma, Wq, Wkv, Wo, Wb,
                                        xn, wqkvT, woT, wbT);
  gemm_qkv<<<dim3(24, 16), 256, 0, stream>>>(xn, wqkvT, wbT, qh, kth, vt);
  attn_kernel<<<512, 256, 0, stream>>>(qh, kth, vt, aout);
  gemm64_bt_f32<<<dim3(16, 32), 256, 0, stream>>>(aout, woT, out, 2048, 1024, 1024);
}